// Round 8
// baseline (568.247 us; speedup 1.0000x reference)
//
#include <hip/hip_runtime.h>
#include <hip/hip_cooperative_groups.h>

namespace cg = cooperative_groups;

typedef __bf16 bf16;
typedef __bf16 bf16_4 __attribute__((ext_vector_type(4)));
typedef __bf16 bf16_8 __attribute__((ext_vector_type(8)));
typedef float f32_4 __attribute__((ext_vector_type(4)));

// async global->LDS, 16B per lane; LDS dest must be wave-uniform base + lane*16
#define GLDS16(g, l) \
  __builtin_amdgcn_global_load_lds((const __attribute__((address_space(1))) unsigned int*)(g), \
                                   (__attribute__((address_space(3))) unsigned int*)(l), 16, 0, 0)

// ---- shared GEMM core: C = A(MxK) * W(NxK)^T tile, glds staging + XOR-swizzled LDS ----
template<int BM>
__device__ __forceinline__ void gemm_core(
    const bf16* __restrict__ Ab, int lda,
    const bf16* __restrict__ Wb, int ldw,
    int K, int m0, int n0, int tid,
    bf16* As, bf16* Bs,
    f32_4 (&acc)[4][(BM == 128) ? 4 : 2])
{
    constexpr int NJ = (BM == 128) ? 4 : 2;
    constexpr int CA = BM * 8;
    const int lane = tid & 63;
    const int wave = tid >> 6;
    const int l15  = lane & 15;
    const int quad = lane >> 4;
    const int WM = (BM == 128) ? (wave >> 1) * 64 : 0;
    const int WN = (BM == 128) ? (wave & 1) * 64 : wave * 32;

#pragma unroll
    for (int i = 0; i < 4; i++)
#pragma unroll
        for (int j = 0; j < NJ; j++) acc[i][j] = (f32_4)(0.0f);

    for (int k0 = 0; k0 < K; k0 += 64) {
#pragma unroll
        for (int it = 0; it < CA / 256; ++it) {
            int p = wave * (CA / 4) + it * 64 + lane;
            int r = p >> 3;
            int q = (p & 7) ^ (r & 7);
            GLDS16(Ab + (long long)(m0 + r) * lda + k0 + q * 8, As + p * 8);
        }
#pragma unroll
        for (int it = 0; it < 4; ++it) {
            int p = wave * 256 + it * 64 + lane;
            int r = p >> 3;
            int q = (p & 7) ^ (r & 7);
            GLDS16(Wb + (long long)(n0 + r) * ldw + k0 + q * 8, Bs + p * 8);
        }
        __syncthreads();

#pragma unroll
        for (int kh = 0; kh < 2; ++kh) {
            bf16_8 af[4], bfr[NJ];
#pragma unroll
            for (int t = 0; t < 4; ++t) {
                int r = WM + t * 16 + l15;
                int q = (kh * 4 + quad) ^ (r & 7);
                af[t] = *reinterpret_cast<const bf16_8*>(&As[r * 64 + q * 8]);
            }
#pragma unroll
            for (int j = 0; j < NJ; ++j) {
                int r = WN + j * 16 + l15;
                int q = (kh * 4 + quad) ^ (r & 7);
                bfr[j] = *reinterpret_cast<const bf16_8*>(&Bs[r * 64 + q * 8]);
            }
#pragma unroll
            for (int i = 0; i < 4; ++i)
#pragma unroll
                for (int j = 0; j < NJ; ++j)
                    acc[i][j] = __builtin_amdgcn_mfma_f32_16x16x32_bf16(af[i], bfr[j], acc[i][j], 0, 0, 0);
        }
        __syncthreads();
    }
}

// =================== ONE persistent cooperative kernel: 7 phases ===================
__global__ __launch_bounds__(256, 2) void fused_mha(
    const float* __restrict__ x,  const float* __restrict__ Wq, const float* __restrict__ bq,
    const float* __restrict__ Wk, const float* __restrict__ bk,
    const float* __restrict__ Wv, const float* __restrict__ bv,
    const float* __restrict__ Wo, const float* __restrict__ bo,
    const float* __restrict__ slopes,
    bf16* __restrict__ x_bf, bf16* __restrict__ wq_bf, bf16* __restrict__ wk_bf,
    bf16* __restrict__ wv_bf, bf16* __restrict__ wo_bf,
    bf16* __restrict__ qh1, bf16* __restrict__ kh1, bf16* __restrict__ v_bf,
    bf16* __restrict__ vt, bf16* __restrict__ attn, bf16* __restrict__ pb,
    float* __restrict__ spart, float* __restrict__ rsinv,
    float* __restrict__ out_f, float* __restrict__ probs_f)
{
    cg::grid_group grid = cg::this_grid();
    __shared__ alignas(16) char smem[32768];
    bf16* As    = (bf16*)smem;
    bf16* Bs64  = (bf16*)(smem + 8192);     // BM=64 layout
    bf16* Bs128 = (bf16*)(smem + 16384);    // BM=128 layout
    const int tid = threadIdx.x;
    const int bid = blockIdx.x;
    const int lane = tid & 63;
    const int wave = tid >> 6;
    const int l15  = lane & 15;
    const int quad = lane >> 4;

    // ---------- P0: f32 -> bf16 converts (x + 4 weights) ----------
    for (int i = bid * 256 + tid; i < 2097152; i += 512 * 256) {
        const float* s; bf16* d; int off;
        if (i < 1048576) { s = x; d = x_bf; off = i; }
        else {
            int j = i - 1048576;
            int sel = j >> 18;
            off = j & 262143;
            s = (sel == 0) ? Wq : (sel == 1) ? Wk : (sel == 2) ? Wv : Wo;
            d = (sel == 0) ? wq_bf : (sel == 1) ? wk_bf : (sel == 2) ? wv_bf : wo_bf;
        }
        float4 v = reinterpret_cast<const float4*>(s)[off];
        bf16_4 o; o.x = (bf16)v.x; o.y = (bf16)v.y; o.z = (bf16)v.z; o.w = (bf16)v.w;
        reinterpret_cast<bf16_4*>(d)[off] = o;
    }
    grid.sync();

    // ---------- P1: V projection (4096x1024), 512 tiles, 1 per block ----------
    {
        int m0 = (bid >> 3) * 64, n0 = (bid & 7) * 128;
        f32_4 acc[4][2];
        gemm_core<64>(x_bf, 1024, wv_bf, 1024, 1024, m0, n0, tid, As, Bs64, acc);
        const int WN = wave * 32;
#pragma unroll
        for (int i = 0; i < 4; i++)
#pragma unroll
            for (int j = 0; j < 2; j++)
#pragma unroll
                for (int rg = 0; rg < 4; rg++) {
                    int m = m0 + i * 16 + quad * 4 + rg;
                    int n = n0 + WN + j * 16 + l15;
                    v_bf[(long long)m * 1024 + n] = (bf16)(acc[i][j][rg] + bv[n]);
                }
    }
    grid.sync();

    // ---------- P2: QK head-1 projections (blocks 0..63)  ||  V transpose (64..511) ----
    if (bid < 64) {
        int sub = bid >> 3, xx = bid & 7;
        int batch = (sub >> 1) & 1, sel = sub >> 2;
        int m0 = (sub & 1) * 64, n0 = xx * 128;
        const bf16* Ab = x_bf + (long long)batch * 2097152LL + 131072LL;  // rows 128..255
        const bf16* Wb = sel ? wk_bf : wq_bf;
        const float* bvec = sel ? bk : bq;
        bf16* op = sel ? kh1 : qh1;
        long long obase = (long long)batch * 131072LL;
        f32_4 acc[4][2];
        gemm_core<64>(Ab, 1024, Wb, 1024, 1024, m0, n0, tid, As, Bs64, acc);
        const int WN = wave * 32;
#pragma unroll
        for (int i = 0; i < 4; i++)
#pragma unroll
            for (int j = 0; j < 2; j++)
#pragma unroll
                for (int rg = 0; rg < 4; rg++) {
                    int m = m0 + i * 16 + quad * 4 + rg;
                    int n = n0 + WN + j * 16 + l15;
                    op[obase + (long long)m * 1024 + n] = (bf16)(acc[i][j][rg] + bvec[n]);
                }
    } else {
        unsigned short* tile = (unsigned short*)smem;   // 64*66*2 = 8448 B
        const unsigned short* vsrc = (const unsigned short*)v_bf;
        unsigned short* vdst = (unsigned short*)vt;
        for (int u = bid - 64; u < 1024; u += 448) {
            int k0 = (u & 31) * 64, h = (u >> 5) & 15, b = u >> 9;
            const unsigned short* src = vsrc + (long long)b * 2097152LL + (long long)h * 131072LL;
#pragma unroll
            for (int p = 0; p < 8; p++) {
                int idx = tid + p * 256;
                int k = idx >> 5, dc = idx & 31;
                ushort2 uu = *reinterpret_cast<const ushort2*>(&src[(long long)(k0 + k) * 64 + dc * 2]);
                tile[(dc * 2) * 66 + k]     = uu.x;
                tile[(dc * 2 + 1) * 66 + k] = uu.y;
            }
            __syncthreads();
            unsigned short* dst = vdst + (long long)b * 2097152LL + (long long)h * 64 * 2048LL + k0;
#pragma unroll
            for (int p = 0; p < 8; p++) {
                int idx = tid + p * 256;
                int d = idx >> 5, kc = idx & 31;
                ushort2 uu;
                uu.x = tile[d * 66 + kc * 2];
                uu.y = tile[d * 66 + kc * 2 + 1];
                *reinterpret_cast<ushort2*>(&dst[(long long)d * 2048 + kc * 2]) = uu;
            }
            __syncthreads();
        }
    }
    grid.sync();

    // ---------- P3: scores head-1 + exp + row partials (512 tiles, BM=128) ----------
    {
        int z = bid >> 8, rem = bid & 255;
        int m0 = (rem >> 4) * 128, n0 = (rem & 15) * 128;
        const bf16* Ab = qh1 + (long long)z * 131072LL;
        const bf16* Wb = kh1 + (long long)z * 131072LL;
        f32_4 acc[4][4];
        gemm_core<128>(Ab, 64, Wb, 64, 64, m0, n0, tid, As, Bs128, acc);
        const int WM = (wave >> 1) * 64;
        const int WN = (wave & 1) * 64;
        const float slope = slopes[1];
        long long obase = (long long)z * 4194304LL;
#pragma unroll
        for (int i = 0; i < 4; i++) {
#pragma unroll
            for (int rg = 0; rg < 4; rg++) {
                int m = m0 + WM + i * 16 + quad * 4 + rg;
                float rowpart = 0.0f;
#pragma unroll
                for (int j = 0; j < 4; j++) {
                    int n = n0 + WN + j * 16 + l15;
                    float v = acc[i][j][rg] * 0.125f - slope * fabsf((float)(m - n));
                    float e = __expf(v);
                    rowpart += e;
                    pb[obase + (long long)m * 2048 + n] = (bf16)e;
                }
                rowpart += __shfl_xor(rowpart, 1, 64);
                rowpart += __shfl_xor(rowpart, 2, 64);
                rowpart += __shfl_xor(rowpart, 4, 64);
                rowpart += __shfl_xor(rowpart, 8, 64);
                if (l15 == 0)
                    spart[((long long)z * 2048 + m) * 32 + (n0 >> 6) + (WN >> 6)] = rowpart;
            }
        }
    }
    grid.sync();

    // ---------- P4: normalize (4096 rows, 8 per block) ----------
    {
        float* invp = (float*)smem;
        for (int r = bid; r < 4096; r += 512) {
            if (tid < 64) {
                float p = (tid < 32) ? spart[(long long)r * 32 + tid] : 0.0f;
#pragma unroll
                for (int o = 1; o <= 32; o <<= 1) p += __shfl_xor(p, o, 64);
                if (tid == 0) { float inv = 1.0f / p; invp[0] = inv; rsinv[r] = inv; }
            }
            __syncthreads();
            float inv = invp[0];
            bf16_8 e = reinterpret_cast<const bf16_8*>(pb + (long long)r * 2048)[tid];
            float4 o0, o1;
            o0.x = (float)e[0] * inv; o0.y = (float)e[1] * inv; o0.z = (float)e[2] * inv; o0.w = (float)e[3] * inv;
            o1.x = (float)e[4] * inv; o1.y = (float)e[5] * inv; o1.z = (float)e[6] * inv; o1.w = (float)e[7] * inv;
            reinterpret_cast<float4*>(probs_f + (long long)r * 2048)[tid * 2]     = o0;
            reinterpret_cast<float4*>(probs_f + (long long)r * 2048)[tid * 2 + 1] = o1;
            __syncthreads();
        }
    }
    grid.sync();

    // ---------- P5: PV (512 tiles): (pb * rsinv) @ vt^T -> flat attn scatter ----------
    {
        int z = bid >> 8, rem = bid & 255;
        int m0 = (rem >> 3) * 64, n0 = (rem & 7) * 128;
        const bf16* Ab = pb + (long long)z * 4194304LL;
        const bf16* Wb = vt + (long long)z * 2097152LL;
        f32_4 acc[4][2];
        gemm_core<64>(Ab, 2048, Wb, 2048, 2048, m0, n0, tid, As, Bs64, acc);
        const int WN = wave * 32;
        long long obase = (long long)z * 2097152LL;
#pragma unroll
        for (int i = 0; i < 4; i++)
#pragma unroll
            for (int j = 0; j < 2; j++)
#pragma unroll
                for (int rg = 0; rg < 4; rg++) {
                    int m = m0 + i * 16 + quad * 4 + rg;
                    int n = n0 + WN + j * 16 + l15;
                    float v = acc[i][j][rg] * rsinv[(long long)z * 2048 + m];
                    long long off = obase + ((long long)(n >> 6)) * 131072LL + (long long)m * 64 + (n & 63);
                    attn[off] = (bf16)v;
                }
    }
    grid.sync();

    // ---------- P6: out projection (4096x1024) f32 + bo -> d_out ----------
    {
        int m0 = (bid >> 3) * 64, n0 = (bid & 7) * 128;
        f32_4 acc[4][2];
        gemm_core<64>(attn, 1024, wo_bf, 1024, 1024, m0, n0, tid, As, Bs64, acc);
        const int WN = wave * 32;
#pragma unroll
        for (int i = 0; i < 4; i++)
#pragma unroll
            for (int j = 0; j < 2; j++)
#pragma unroll
                for (int rg = 0; rg < 4; rg++) {
                    int m = m0 + i * 16 + quad * 4 + rg;
                    int n = n0 + WN + j * 16 + l15;
                    out_f[(long long)m * 1024 + n] = acc[i][j][rg] + bo[n];
                }
    }
}

// =================== fallback path (Round-7 verified 7-launch pipeline) ===================
__global__ __launch_bounds__(256) void convert_all(
    const float* __restrict__ x, const float* __restrict__ wq, const float* __restrict__ wk,
    const float* __restrict__ wv, const float* __restrict__ wo,
    bf16* __restrict__ xb, bf16* __restrict__ wqb, bf16* __restrict__ wkb,
    bf16* __restrict__ wvb, bf16* __restrict__ wob)
{
    int i = blockIdx.x * 256 + threadIdx.x;
    const float* s; bf16* d; int off;
    if (i < 1048576) { s = x; d = xb; off = i; }
    else {
        int j = i - 1048576;
        int sel = j >> 18;
        off = j & 262143;
        s = (sel == 0) ? wq : (sel == 1) ? wk : (sel == 2) ? wv : wo;
        d = (sel == 0) ? wqb : (sel == 1) ? wkb : (sel == 2) ? wvb : wob;
    }
    float4 v = reinterpret_cast<const float4*>(s)[off];
    bf16_4 o; o.x = (bf16)v.x; o.y = (bf16)v.y; o.z = (bf16)v.z; o.w = (bf16)v.w;
    reinterpret_cast<bf16_4*>(d)[off] = o;
}

template<int BM, int MODE>
__global__ __launch_bounds__(256) void gemm_glds(
    const bf16* __restrict__ A, int lda, long long aBatch,
    const bf16* __restrict__ W, int ldw, long long wBatch,
    const float* __restrict__ bias,
    void* __restrict__ outp, long long outBatch,
    int N, int K, float scale, const float* __restrict__ slopes,
    const bf16* __restrict__ W2, const float* __restrict__ bias2, void* __restrict__ out2,
    const bf16* __restrict__ W3, const float* __restrict__ bias3, void* __restrict__ out3,
    float* __restrict__ spart, const float* __restrict__ rsinv)
{
    constexpr int NJ = (BM == 128) ? 4 : 2;
    __shared__ alignas(16) bf16 As[BM * 64];
    __shared__ alignas(16) bf16 Bs[128 * 64];
    const int tid = threadIdx.x;
    const int lane = tid & 63;
    const int wave = tid >> 6;
    const int l15 = lane & 15;
    const int quad = lane >> 4;
    const int n0 = blockIdx.x * 128;
    const int z = blockIdx.z;
    const int WM = (BM == 128) ? (wave >> 1) * 64 : 0;
    const int WN = (BM == 128) ? (wave & 1) * 64 : wave * 32;

    int m0;
    const bf16* Ab; const bf16* Wb; const float* bvec; void* op;
    long long obase;
    if (MODE == 11) {
        int y = blockIdx.y;
        if (y < 64) { m0 = y * 64; Ab = A; Wb = W; bvec = bias; op = outp; obase = 0; }
        else {
            int sub = y - 64;
            int batch = (sub >> 1) & 1;
            int sel = sub >> 2;
            m0 = (sub & 1) * 64;
            Ab = A + (long long)batch * 2097152LL + 131072LL;
            Wb = sel ? W3 : W2; bvec = sel ? bias3 : bias2; op = sel ? out3 : out2;
            obase = (long long)batch * 131072LL;
        }
    } else {
        m0 = blockIdx.y * BM;
        Ab = A + (long long)z * aBatch; Wb = W + (long long)z * wBatch;
        bvec = bias; op = outp; obase = (long long)z * outBatch;
    }

    f32_4 acc[4][NJ];
#pragma unroll
    for (int i = 0; i < 4; i++)
#pragma unroll
        for (int j = 0; j < NJ; j++) acc[i][j] = (f32_4)(0.0f);

    for (int k0 = 0; k0 < K; k0 += 64) {
#pragma unroll
        for (int it = 0; it < (BM * 8) / 256; ++it) {
            int p = wave * (BM * 2) + it * 64 + lane;
            int r = p >> 3;
            int q = (p & 7) ^ (r & 7);
            GLDS16(Ab + (long long)(m0 + r) * lda + k0 + q * 8, As + p * 8);
        }
#pragma unroll
        for (int it = 0; it < 4; ++it) {
            int p = wave * 256 + it * 64 + lane;
            int r = p >> 3;
            int q = (p & 7) ^ (r & 7);
            GLDS16(Wb + (long long)(n0 + r) * ldw + k0 + q * 8, Bs + p * 8);
        }
        __syncthreads();
#pragma unroll
        for (int kh = 0; kh < 2; ++kh) {
            bf16_8 af[4], bfr[NJ];
#pragma unroll
            for (int t = 0; t < 4; ++t) {
                int r = WM + t * 16 + l15;
                int q = (kh * 4 + quad) ^ (r & 7);
                af[t] = *reinterpret_cast<const bf16_8*>(&As[r * 64 + q * 8]);
            }
#pragma unroll
            for (int j = 0; j < NJ; ++j) {
                int r = WN + j * 16 + l15;
                int q = (kh * 4 + quad) ^ (r & 7);
                bfr[j] = *reinterpret_cast<const bf16_8*>(&Bs[r * 64 + q * 8]);
            }
#pragma unroll
            for (int i = 0; i < 4; ++i)
#pragma unroll
                for (int j = 0; j < NJ; ++j)
                    acc[i][j] = __builtin_amdgcn_mfma_f32_16x16x32_bf16(af[i], bfr[j], acc[i][j], 0, 0, 0);
        }
        __syncthreads();
    }

    if constexpr (MODE == 9) {
        const float slope = slopes[1];
#pragma unroll
        for (int i = 0; i < 4; i++) {
#pragma unroll
            for (int rg = 0; rg < 4; rg++) {
                int m = m0 + WM + i * 16 + quad * 4 + rg;
                float rowpart = 0.0f;
#pragma unroll
                for (int j = 0; j < NJ; j++) {
                    int n = n0 + WN + j * 16 + l15;
                    float v = acc[i][j][rg] * scale - slope * fabsf((float)(m - n));
                    float e = __expf(v);
                    rowpart += e;
                    ((bf16*)op)[obase + (long long)m * N + n] = (bf16)e;
                }
                rowpart += __shfl_xor(rowpart, 1, 64);
                rowpart += __shfl_xor(rowpart, 2, 64);
                rowpart += __shfl_xor(rowpart, 4, 64);
                rowpart += __shfl_xor(rowpart, 8, 64);
                if (l15 == 0)
                    spart[((long long)z * 2048 + m) * 32 + (n0 >> 6) + (WN >> 6)] = rowpart;
            }
        }
        return;
    }

#pragma unroll
    for (int i = 0; i < 4; i++) {
#pragma unroll
        for (int j = 0; j < NJ; j++) {
#pragma unroll
            for (int rg = 0; rg < 4; rg++) {
                int m = m0 + WM + i * 16 + quad * 4 + rg;
                int n = n0 + WN + j * 16 + l15;
                float v = acc[i][j][rg];
                if (MODE == 11) {
                    v += bvec[n];
                    ((bf16*)op)[obase + (long long)m * 1024 + n] = (bf16)v;
                } else if (MODE == 1) {
                    if (bvec) v += bvec[n];
                    ((float*)op)[obase + (long long)m * N + n] = v;
                } else {
                    v *= rsinv[(long long)z * 2048 + m];
                    long long off = obase + ((long long)(n >> 6)) * 131072LL + (long long)m * 64 + (n & 63);
                    ((bf16*)op)[off] = (bf16)v;
                }
            }
        }
    }
}

__global__ __launch_bounds__(256) void transpose_v(const unsigned short* __restrict__ v,
                                                   unsigned short* __restrict__ vt) {
    __shared__ unsigned short tile[64 * 66];
    const int t = threadIdx.x;
    const int k0 = blockIdx.x * 64;
    const int h = blockIdx.y;
    const int b = blockIdx.z;
    const unsigned short* src = v + (long long)b * 2097152LL + (long long)h * 131072LL;
#pragma unroll
    for (int p = 0; p < 8; p++) {
        int idx = t + p * 256;
        int k = idx >> 5, dc = idx & 31;
        ushort2 u = *reinterpret_cast<const ushort2*>(&src[(long long)(k0 + k) * 64 + dc * 2]);
        tile[(dc * 2) * 66 + k] = u.x;
        tile[(dc * 2 + 1) * 66 + k] = u.y;
    }
    __syncthreads();
    unsigned short* dst = vt + (long long)b * 2097152LL + (long long)h * 64 * 2048LL + k0;
#pragma unroll
    for (int p = 0; p < 8; p++) {
        int idx = t + p * 256;
        int d = idx >> 5, kc = idx & 31;
        ushort2 u;
        u.x = tile[d * 66 + kc * 2];
        u.y = tile[d * 66 + kc * 2 + 1];
        *reinterpret_cast<ushort2*>(&dst[(long long)d * 2048 + kc * 2]) = u;
    }
}

__global__ __launch_bounds__(256) void normalize_rows(const float* __restrict__ spart,
                                                      const bf16* __restrict__ pb,
                                                      float* __restrict__ probs_f,
                                                      float* __restrict__ rsinv) {
    __shared__ float inv_s;
    const long long row = blockIdx.x;
    const int t = threadIdx.x;
    if (t < 64) {
        float p = (t < 32) ? spart[row * 32 + t] : 0.0f;
#pragma unroll
        for (int o = 1; o <= 32; o <<= 1) p += __shfl_xor(p, o, 64);
        if (t == 0) { float inv = 1.0f / p; inv_s = inv; rsinv[row] = inv; }
    }
    __syncthreads();
    const float inv = inv_s;
    bf16_8 e = reinterpret_cast<const bf16_8*>(pb + row * 2048LL)[t];
    float4 o0, o1;
    o0.x = (float)e[0] * inv; o0.y = (float)e[1] * inv; o0.z = (float)e[2] * inv; o0.w = (float)e[3] * inv;
    o1.x = (float)e[4] * inv; o1.y = (float)e[5] * inv; o1.z = (float)e[6] * inv; o1.w = (float)e[7] * inv;
    reinterpret_cast<float4*>(probs_f + row * 2048LL)[t * 2] = o0;
    reinterpret_cast<float4*>(probs_f + row * 2048LL)[t * 2 + 1] = o1;
}

// ---------------- launcher ----------------
extern "C" void kernel_launch(void* const* d_in, const int* in_sizes, int n_in,
                              void* d_out, int out_size, void* d_ws, size_t ws_size,
                              hipStream_t stream) {
    const float* x      = (const float*)d_in[0];
    const float* Wq     = (const float*)d_in[1];
    const float* bq     = (const float*)d_in[2];
    const float* Wk     = (const float*)d_in[3];
    const float* bk     = (const float*)d_in[4];
    const float* Wv     = (const float*)d_in[5];
    const float* bv     = (const float*)d_in[6];
    const float* Wo     = (const float*)d_in[7];
    const float* bo     = (const float*)d_in[8];
    const float* slopes = (const float*)d_in[9];

    char* w = (char*)d_ws;
    bf16* x_bf  = (bf16*)w;  w += 4096LL * 1024 * 2;
    bf16* wq_bf = (bf16*)w;  w += 1024LL * 1024 * 2;
    bf16* wk_bf = (bf16*)w;  w += 1024LL * 1024 * 2;
    bf16* wv_bf = (bf16*)w;  w += 1024LL * 1024 * 2;
    bf16* wo_bf = (bf16*)w;  w += 1024LL * 1024 * 2;
    bf16* qh1   = (bf16*)w;  w += 2LL * 131072 * 2;
    bf16* kh1   = (bf16*)w;  w += 2LL * 131072 * 2;
    bf16* v_bf  = (bf16*)w;  w += 4096LL * 1024 * 2;
    bf16* vt    = (bf16*)w;  w += 2LL * 1024 * 2048 * 2;
    bf16* attn  = (bf16*)w;  w += 4096LL * 1024 * 2;
    bf16* pb    = (bf16*)w;  w += 2LL * 2048 * 2048 * 2;
    float* spart = (float*)w; w += 4096LL * 32 * 4;
    float* rsinv = (float*)w; w += 4096LL * 4;

    float* out_f   = (float*)d_out;
    float* probs_f = (float*)d_out + 4194304LL;

    void* args[] = {
        (void*)&x, (void*)&Wq, (void*)&bq, (void*)&Wk, (void*)&bk,
        (void*)&Wv, (void*)&bv, (void*)&Wo, (void*)&bo, (void*)&slopes,
        (void*)&x_bf, (void*)&wq_bf, (void*)&wk_bf, (void*)&wv_bf, (void*)&wo_bf,
        (void*)&qh1, (void*)&kh1, (void*)&v_bf, (void*)&vt, (void*)&attn, (void*)&pb,
        (void*)&spart, (void*)&rsinv, (void*)&out_f, (void*)&probs_f
    };
    hipError_t err = hipLaunchCooperativeKernel((void*)fused_mha, dim3(512), dim3(256),
                                                args, 0, stream);
    if (err != hipSuccess) {
        // fallback: verified 7-launch pipeline
        convert_all<<<8192, 256, 0, stream>>>(x, Wq, Wk, Wv, Wo, x_bf, wq_bf, wk_bf, wv_bf, wo_bf);
        gemm_glds<64, 11><<<dim3(8, 72, 1), 256, 0, stream>>>(
            x_bf, 1024, 0LL, wv_bf, 1024, 0LL, bv, v_bf, 0LL, 1024, 1024, 1.0f, nullptr,
            wq_bf, bq, qh1, wk_bf, bk, kh1, nullptr, nullptr);
        transpose_v<<<dim3(32, 16, 2), 256, 0, stream>>>((const unsigned short*)v_bf,
                                                         (unsigned short*)vt);
        gemm_glds<128, 9><<<dim3(16, 16, 2), 256, 0, stream>>>(
            qh1, 64, 131072LL, kh1, 64, 131072LL, nullptr,
            pb, 4194304LL, 2048, 64, 0.125f, slopes,
            nullptr, nullptr, nullptr, nullptr, nullptr, nullptr, spart, nullptr);
        normalize_rows<<<4096, 256, 0, stream>>>(spart, pb, probs_f, rsinv);
        gemm_glds<64, 6><<<dim3(8, 32, 2), 256, 0, stream>>>(
            pb, 2048, 4194304LL, vt, 2048, 2097152LL, nullptr,
            attn, 2097152LL, 1024, 2048, 1.0f, nullptr,
            nullptr, nullptr, nullptr, nullptr, nullptr, nullptr, nullptr, rsinv);
        gemm_glds<64, 1><<<dim3(8, 64, 1), 256, 0, stream>>>(
            attn, 1024, 0LL, wo_bf, 1024, 0LL, bo,
            out_f, 0LL, 1024, 1024, 1.0f, nullptr,
            nullptr, nullptr, nullptr, nullptr, nullptr, nullptr, nullptr, nullptr);
    }
}

// Round 9
// 179.194 us; speedup vs baseline: 3.1711x; 3.1711x over previous
//
#include <hip/hip_runtime.h>

typedef __bf16 bf16;
typedef __bf16 bf16_4 __attribute__((ext_vector_type(4)));
typedef __bf16 bf16_8 __attribute__((ext_vector_type(8)));
typedef float f32_4 __attribute__((ext_vector_type(4)));

// async global->LDS, 16B per lane; LDS dest must be wave-uniform base + lane*16
#define GLDS16(g, l) \
  __builtin_amdgcn_global_load_lds((const __attribute__((address_space(1))) unsigned int*)(g), \
                                   (__attribute__((address_space(3))) unsigned int*)(l), 16, 0, 0)

// ---------------- fused f32 -> bf16 convert for x + 4 weights ----------------
__global__ __launch_bounds__(256) void convert_all(
    const float* __restrict__ x, const float* __restrict__ wq, const float* __restrict__ wk,
    const float* __restrict__ wv, const float* __restrict__ wo,
    bf16* __restrict__ xb, bf16* __restrict__ wqb, bf16* __restrict__ wkb,
    bf16* __restrict__ wvb, bf16* __restrict__ wob)
{
    int i = blockIdx.x * 256 + threadIdx.x;     // 0 .. 2097151 float4 units
    const float* s; bf16* d; int off;
    if (i < 1048576) { s = x; d = xb; off = i; }
    else {
        int j = i - 1048576;
        int sel = j >> 18;
        off = j & 262143;
        s = (sel == 0) ? wq : (sel == 1) ? wk : (sel == 2) ? wv : wo;
        d = (sel == 0) ? wqb : (sel == 1) ? wkb : (sel == 2) ? wvb : wob;
    }
    float4 v = reinterpret_cast<const float4*>(s)[off];
    bf16_4 o; o.x = (bf16)v.x; o.y = (bf16)v.y; o.z = (bf16)v.z; o.w = (bf16)v.w;
    reinterpret_cast<bf16_4*>(d)[off] = o;
}

// ---- shared GEMM core: C = A(MxK) * W(NxK)^T tile, glds staging + XOR-swizzled LDS ----
template<int BM>
__device__ __forceinline__ void gemm_core(
    const bf16* __restrict__ Ab, int lda,
    const bf16* __restrict__ Wb, int ldw,
    int K, int m0, int n0, int tid,
    bf16* As, bf16* Bs,
    f32_4 (&acc)[4][(BM == 128) ? 4 : 2])
{
    constexpr int NJ = (BM == 128) ? 4 : 2;
    constexpr int CA = BM * 8;
    const int lane = tid & 63;
    const int wave = tid >> 6;
    const int l15  = lane & 15;
    const int quad = lane >> 4;
    const int WM = (BM == 128) ? (wave >> 1) * 64 : 0;
    const int WN = (BM == 128) ? (wave & 1) * 64 : wave * 32;

#pragma unroll
    for (int i = 0; i < 4; i++)
#pragma unroll
        for (int j = 0; j < NJ; j++) acc[i][j] = (f32_4)(0.0f);

    for (int k0 = 0; k0 < K; k0 += 64) {
#pragma unroll
        for (int it = 0; it < CA / 256; ++it) {
            int p = wave * (CA / 4) + it * 64 + lane;
            int r = p >> 3;
            int q = (p & 7) ^ (r & 7);
            GLDS16(Ab + (long long)(m0 + r) * lda + k0 + q * 8, As + p * 8);
        }
#pragma unroll
        for (int it = 0; it < 4; ++it) {
            int p = wave * 256 + it * 64 + lane;
            int r = p >> 3;
            int q = (p & 7) ^ (r & 7);
            GLDS16(Wb + (long long)(n0 + r) * ldw + k0 + q * 8, Bs + p * 8);
        }
        __syncthreads();

#pragma unroll
        for (int kh = 0; kh < 2; ++kh) {
            bf16_8 af[4], bfr[NJ];
#pragma unroll
            for (int t = 0; t < 4; ++t) {
                int r = WM + t * 16 + l15;
                int q = (kh * 4 + quad) ^ (r & 7);
                af[t] = *reinterpret_cast<const bf16_8*>(&As[r * 64 + q * 8]);
            }
#pragma unroll
            for (int j = 0; j < NJ; ++j) {
                int r = WN + j * 16 + l15;
                int q = (kh * 4 + quad) ^ (r & 7);
                bfr[j] = *reinterpret_cast<const bf16_8*>(&Bs[r * 64 + q * 8]);
            }
#pragma unroll
            for (int i = 0; i < 4; ++i)
#pragma unroll
                for (int j = 0; j < NJ; ++j)
                    acc[i][j] = __builtin_amdgcn_mfma_f32_16x16x32_bf16(af[i], bfr[j], acc[i][j], 0, 0, 0);
        }
        __syncthreads();
    }
}

// -------- merged projections (Round-7 verified MODE 11): V full + Q/K head-1 --------
__global__ __launch_bounds__(256) void proj_merged(
    const bf16* __restrict__ x_bf,
    const bf16* __restrict__ wv_bf, const float* __restrict__ bv, bf16* __restrict__ v_bf,
    const bf16* __restrict__ wq_bf, const float* __restrict__ bq, bf16* __restrict__ qh1,
    const bf16* __restrict__ wk_bf, const float* __restrict__ bk, bf16* __restrict__ kh1)
{
    __shared__ alignas(16) bf16 As[64 * 64];
    __shared__ alignas(16) bf16 Bs[128 * 64];
    const int tid = threadIdx.x;
    const int lane = tid & 63, wave = tid >> 6, l15 = lane & 15, quad = lane >> 4;
    const int n0 = blockIdx.x * 128;

    int m0;
    const bf16* Ab; const bf16* Wb; const float* bvec; bf16* op;
    long long obase;
    int y = blockIdx.y;
    if (y < 64) { m0 = y * 64; Ab = x_bf; Wb = wv_bf; bvec = bv; op = v_bf; obase = 0; }
    else {
        int sub = y - 64;
        int batch = (sub >> 1) & 1;
        int sel = sub >> 2;
        m0 = (sub & 1) * 64;
        Ab = x_bf + (long long)batch * 2097152LL + 131072LL;   // rows 128..255 of batch slab
        Wb = sel ? wk_bf : wq_bf;
        bvec = sel ? bk : bq;
        op = sel ? kh1 : qh1;
        obase = (long long)batch * 131072LL;
    }

    f32_4 acc[4][2];
    gemm_core<64>(Ab, 1024, Wb, 1024, 1024, m0, n0, tid, As, Bs, acc);

    const int WN = wave * 32;
#pragma unroll
    for (int i = 0; i < 4; i++)
#pragma unroll
        for (int j = 0; j < 2; j++)
#pragma unroll
            for (int rg = 0; rg < 4; rg++) {
                int m = m0 + i * 16 + quad * 4 + rg;
                int n = n0 + WN + j * 16 + l15;
                op[obase + (long long)m * 1024 + n] = (bf16)(acc[i][j][rg] + bvec[n]);
            }
}

// -------- scores head-1 + exp + row partials, THEN inline V transpose (2 tiles/block) ---
__global__ __launch_bounds__(256) void scores_tr(
    const bf16* __restrict__ qh1, const bf16* __restrict__ kh1,
    const float* __restrict__ slopes,
    bf16* __restrict__ pb, float* __restrict__ spart,
    const unsigned short* __restrict__ v_bf, unsigned short* __restrict__ vt)
{
    __shared__ alignas(16) char smem[32768];
    bf16* As = (bf16*)smem;
    bf16* Bs = (bf16*)(smem + 16384);
    const int tid = threadIdx.x;
    const int lane = tid & 63, wave = tid >> 6, l15 = lane & 15, quad = lane >> 4;
    const int n0 = blockIdx.x * 128;
    const int m0 = blockIdx.y * 128;
    const int z  = blockIdx.z;

    f32_4 acc[4][4];
    gemm_core<128>(qh1 + (long long)z * 131072LL, 64,
                   kh1 + (long long)z * 131072LL, 64, 64, m0, n0, tid, As, Bs, acc);

    const int WM = (wave >> 1) * 64;
    const int WN = (wave & 1) * 64;
    const float slope = slopes[1];
    long long obase = (long long)z * 4194304LL;
#pragma unroll
    for (int i = 0; i < 4; i++) {
#pragma unroll
        for (int rg = 0; rg < 4; rg++) {
            int m = m0 + WM + i * 16 + quad * 4 + rg;
            float rowpart = 0.0f;
#pragma unroll
            for (int j = 0; j < 4; j++) {
                int n = n0 + WN + j * 16 + l15;
                float v = acc[i][j][rg] * 0.125f - slope * fabsf((float)(m - n));
                float e = __expf(v);
                rowpart += e;
                pb[obase + (long long)m * 2048 + n] = (bf16)e;
            }
            rowpart += __shfl_xor(rowpart, 1, 64);
            rowpart += __shfl_xor(rowpart, 2, 64);
            rowpart += __shfl_xor(rowpart, 4, 64);
            rowpart += __shfl_xor(rowpart, 8, 64);
            if (l15 == 0)
                spart[((long long)z * 2048 + m) * 32 + (n0 >> 6) + (WN >> 6)] = rowpart;
        }
    }

    // ---- inline V transpose (flat-reshape mapping), 2 of 1024 tiles per block ----
    unsigned short* tile = (unsigned short*)smem;    // As region free after gemm_core
    int flat = z * 256 + blockIdx.y * 16 + blockIdx.x;   // 0..511
#pragma unroll
    for (int uu = 0; uu < 2; ++uu) {
        int u = flat * 2 + uu;                           // 0..1023
        int k0 = (u & 31) * 64, h = (u >> 5) & 15, b = u >> 9;
        const unsigned short* src = v_bf + (long long)b * 2097152LL + (long long)h * 131072LL;
#pragma unroll
        for (int p = 0; p < 8; p++) {
            int idx = tid + p * 256;
            int k = idx >> 5, dc = idx & 31;
            ushort2 w = *reinterpret_cast<const ushort2*>(&src[(long long)(k0 + k) * 64 + dc * 2]);
            tile[(dc * 2) * 66 + k]     = w.x;
            tile[(dc * 2 + 1) * 66 + k] = w.y;
        }
        __syncthreads();
        unsigned short* dst = vt + (long long)b * 2097152LL + (long long)h * 64 * 2048LL + k0;
#pragma unroll
        for (int p = 0; p < 8; p++) {
            int idx = tid + p * 256;
            int d = idx >> 5, kc = idx & 31;
            ushort2 w;
            w.x = tile[d * 66 + kc * 2];
            w.y = tile[d * 66 + kc * 2 + 1];
            *reinterpret_cast<ushort2*>(&dst[(long long)d * 2048 + kc * 2]) = w;
        }
        __syncthreads();
    }
}

// -------- PV fused: rsinv prologue + probs_f f32 writes during staging + attn scatter ---
__global__ __launch_bounds__(256) void pv_fused(
    const bf16* __restrict__ pb, const bf16* __restrict__ vt,
    const float* __restrict__ spart,
    bf16* __restrict__ attn, float* __restrict__ probs_f)
{
    __shared__ alignas(16) bf16 As[64 * 64];
    __shared__ alignas(16) bf16 Bs[128 * 64];
    __shared__ float rs[64];
    const int tid = threadIdx.x;
    const int lane = tid & 63, wave = tid >> 6, l15 = lane & 15, quad = lane >> 4;
    const int nx = blockIdx.x;          // n-tile AND probs k-slice index (both 8-wide)
    const int n0 = nx * 128;
    const int m0 = blockIdx.y * 64;
    const int z  = blockIdx.z;

    // prologue: rs[r] = 1 / sum_j spart[z*2048+m0+r][j]
    {
        int r = tid >> 2, part = tid & 3;
        const float* sp = spart + ((long long)z * 2048 + m0 + r) * 32 + part * 8;
        float4 a = *reinterpret_cast<const float4*>(sp);
        float4 b = *reinterpret_cast<const float4*>(sp + 4);
        float v = a.x + a.y + a.z + a.w + b.x + b.y + b.z + b.w;
        v += __shfl_xor(v, 1, 64);
        v += __shfl_xor(v, 2, 64);
        if (part == 0) rs[r] = 1.0f / v;
    }
    __syncthreads();

    const bf16* Ab = pb + (long long)z * 4194304LL;
    const bf16* Wb = vt + (long long)z * 2097152LL;

    f32_4 acc[4][2];
#pragma unroll
    for (int i = 0; i < 4; i++)
#pragma unroll
        for (int j = 0; j < 2; j++) acc[i][j] = (f32_4)(0.0f);

    for (int k0 = 0; k0 < 2048; k0 += 64) {
#pragma unroll
        for (int it = 0; it < 2; ++it) {
            int p = wave * 128 + it * 64 + lane;
            int r = p >> 3, q = (p & 7) ^ (r & 7);
            GLDS16(Ab + (long long)(m0 + r) * 2048 + k0 + q * 8, As + p * 8);
        }
#pragma unroll
        for (int it = 0; it < 4; ++it) {
            int p = wave * 256 + it * 64 + lane;
            int r = p >> 3, q = (p & 7) ^ (r & 7);
            GLDS16(Wb + (long long)(n0 + r) * 2048 + k0 + q * 8, Bs + p * 8);
        }
        __syncthreads();

        // write probs_f (f32, normalized) for this block's 256-col k-slice
        if ((k0 >> 8) == nx) {
#pragma unroll
            for (int s0 = 0; s0 < 2; ++s0) {
                int s = tid + s0 * 256;          // 0..511
                int r = s >> 3, q = s & 7;
                bf16_8 e = *reinterpret_cast<const bf16_8*>(&As[r * 64 + (q ^ (r & 7)) * 8]);
                float inv = rs[r];
                float4 o0, o1;
                o0.x = (float)e[0] * inv; o0.y = (float)e[1] * inv;
                o0.z = (float)e[2] * inv; o0.w = (float)e[3] * inv;
                o1.x = (float)e[4] * inv; o1.y = (float)e[5] * inv;
                o1.z = (float)e[6] * inv; o1.w = (float)e[7] * inv;
                long long base = ((long long)z * 2048 + m0 + r) * 2048 + k0 + q * 8;
                *reinterpret_cast<float4*>(&probs_f[base])     = o0;
                *reinterpret_cast<float4*>(&probs_f[base + 4]) = o1;
            }
        }

#pragma unroll
        for (int kh = 0; kh < 2; ++kh) {
            bf16_8 af[4], bfr[2];
#pragma unroll
            for (int t = 0; t < 4; ++t) {
                int r = t * 16 + l15;
                int q = (kh * 4 + quad) ^ (r & 7);
                af[t] = *reinterpret_cast<const bf16_8*>(&As[r * 64 + q * 8]);
            }
            const int WN = wave * 32;
#pragma unroll
            for (int j = 0; j < 2; ++j) {
                int r = WN + j * 16 + l15;
                int q = (kh * 4 + quad) ^ (r & 7);
                bfr[j] = *reinterpret_cast<const bf16_8*>(&Bs[r * 64 + q * 8]);
            }
#pragma unroll
            for (int i = 0; i < 4; ++i)
#pragma unroll
                for (int j = 0; j < 2; ++j)
                    acc[i][j] = __builtin_amdgcn_mfma_f32_16x16x32_bf16(af[i], bfr[j], acc[i][j], 0, 0, 0);
        }
        __syncthreads();
    }

    // epilogue: scale by rs[row], scatter to flat attn layout
    const int WN = wave * 32;
    long long obase = (long long)z * 2097152LL;
#pragma unroll
    for (int i = 0; i < 4; i++)
#pragma unroll
        for (int j = 0; j < 2; j++)
#pragma unroll
            for (int rg = 0; rg < 4; rg++) {
                int ml = i * 16 + quad * 4 + rg;
                int m = m0 + ml;
                int n = n0 + WN + j * 16 + l15;
                float v = acc[i][j][rg] * rs[ml];
                long long off = obase + ((long long)(n >> 6)) * 131072LL + (long long)m * 64 + (n & 63);
                attn[off] = (bf16)v;
            }
}

// -------- out projection (Round-7 verified MODE 1): f32 out + bias --------
__global__ __launch_bounds__(256) void out_proj(
    const bf16* __restrict__ attn, const bf16* __restrict__ wo_bf,
    const float* __restrict__ bo, float* __restrict__ out_f)
{
    __shared__ alignas(16) bf16 As[64 * 64];
    __shared__ alignas(16) bf16 Bs[128 * 64];
    const int tid = threadIdx.x;
    const int lane = tid & 63, wave = tid >> 6, l15 = lane & 15, quad = lane >> 4;
    const int n0 = blockIdx.x * 128;
    const int m0 = blockIdx.y * 64;

    f32_4 acc[4][2];
    gemm_core<64>(attn, 1024, wo_bf, 1024, 1024, m0, n0, tid, As, Bs, acc);

    const int WN = wave * 32;
#pragma unroll
    for (int i = 0; i < 4; i++)
#pragma unroll
        for (int j = 0; j < 2; j++)
#pragma unroll
            for (int rg = 0; rg < 4; rg++) {
                int m = m0 + i * 16 + quad * 4 + rg;
                int n = n0 + WN + j * 16 + l15;
                out_f[(long long)m * 1024 + n] = acc[i][j][rg] + bo[n];
            }
}

// ---------------- launcher: 5 launches ----------------
extern "C" void kernel_launch(void* const* d_in, const int* in_sizes, int n_in,
                              void* d_out, int out_size, void* d_ws, size_t ws_size,
                              hipStream_t stream) {
    const float* x      = (const float*)d_in[0];
    const float* Wq     = (const float*)d_in[1];
    const float* bq     = (const float*)d_in[2];
    const float* Wk     = (const float*)d_in[3];
    const float* bk     = (const float*)d_in[4];
    const float* Wv     = (const float*)d_in[5];
    const float* bv     = (const float*)d_in[6];
    const float* Wo     = (const float*)d_in[7];
    const float* bo     = (const float*)d_in[8];
    const float* slopes = (const float*)d_in[9];

    // B=2, S=2048, E=1024, H=16, hd=64
    char* w = (char*)d_ws;
    bf16* x_bf  = (bf16*)w;  w += 4096LL * 1024 * 2;
    bf16* wq_bf = (bf16*)w;  w += 1024LL * 1024 * 2;
    bf16* wk_bf = (bf16*)w;  w += 1024LL * 1024 * 2;
    bf16* wv_bf = (bf16*)w;  w += 1024LL * 1024 * 2;
    bf16* wo_bf = (bf16*)w;  w += 1024LL * 1024 * 2;
    bf16* qh1   = (bf16*)w;  w += 2LL * 131072 * 2;
    bf16* kh1   = (bf16*)w;  w += 2LL * 131072 * 2;
    bf16* v_bf  = (bf16*)w;  w += 4096LL * 1024 * 2;
    bf16* vt    = (bf16*)w;  w += 2LL * 1024 * 2048 * 2;
    bf16* attn  = (bf16*)w;  w += 4096LL * 1024 * 2;
    bf16* pb    = (bf16*)w;  w += 2LL * 2048 * 2048 * 2;
    float* spart = (float*)w; w += 4096LL * 32 * 4;

    float* out_f   = (float*)d_out;                // (B,S,E)
    float* probs_f = (float*)d_out + 4194304LL;    // (B,1,S,S)

    // 1) converts
    convert_all<<<8192, 256, 0, stream>>>(x, Wq, Wk, Wv, Wo, x_bf, wq_bf, wk_bf, wv_bf, wo_bf);

    // 2) merged projections: V full + Q/K head-1
    proj_merged<<<dim3(8, 72, 1), 256, 0, stream>>>(
        x_bf, wv_bf, bv, v_bf, wq_bf, bq, qh1, wk_bf, bk, kh1);

    // 3) scores + exp + spart, then inline V transpose
    scores_tr<<<dim3(16, 16, 2), 256, 0, stream>>>(
        qh1, kh1, slopes, pb, spart,
        (const unsigned short*)v_bf, (unsigned short*)vt);

    // 4) PV fused: rsinv from spart, probs_f (d_out), attn scatter
    pv_fused<<<dim3(8, 32, 2), 256, 0, stream>>>(pb, vt, spart, attn, probs_f);

    // 5) out projection -> d_out
    out_proj<<<dim3(8, 64, 1), 256, 0, stream>>>(attn, wo_bf, bo, out_f);
}

// Round 10
// 177.389 us; speedup vs baseline: 3.2034x; 1.0102x over previous
//
#include <hip/hip_runtime.h>

typedef __bf16 bf16;
typedef __bf16 bf16_4 __attribute__((ext_vector_type(4)));
typedef __bf16 bf16_8 __attribute__((ext_vector_type(8)));
typedef float f32_4 __attribute__((ext_vector_type(4)));

// async global->LDS, 16B per lane; LDS dest must be wave-uniform base + lane*16
#define GLDS16(g, l) \
  __builtin_amdgcn_global_load_lds((const __attribute__((address_space(1))) unsigned int*)(g), \
                                   (__attribute__((address_space(3))) unsigned int*)(l), 16, 0, 0)

// ---------------- fused f32 -> bf16 convert (grid-stride) ----------------
__global__ __launch_bounds__(256) void convert_all(
    const float* __restrict__ x, const float* __restrict__ wq, const float* __restrict__ wk,
    const float* __restrict__ wv, const float* __restrict__ wo,
    bf16* __restrict__ xb, bf16* __restrict__ wqb, bf16* __restrict__ wkb,
    bf16* __restrict__ wvb, bf16* __restrict__ wob)
{
    for (int i = blockIdx.x * 256 + threadIdx.x; i < 2097152; i += 2048 * 256) {
        const float* s; bf16* d; int off;
        if (i < 1048576) { s = x; d = xb; off = i; }
        else {
            int j = i - 1048576;
            int sel = j >> 18;
            off = j & 262143;
            s = (sel == 0) ? wq : (sel == 1) ? wk : (sel == 2) ? wv : wo;
            d = (sel == 0) ? wqb : (sel == 1) ? wkb : (sel == 2) ? wvb : wob;
        }
        float4 v = reinterpret_cast<const float4*>(s)[off];
        bf16_4 o; o.x = (bf16)v.x; o.y = (bf16)v.y; o.z = (bf16)v.z; o.w = (bf16)v.w;
        reinterpret_cast<bf16_4*>(d)[off] = o;
    }
}

// ---- shared GEMM core: C = A(MxK)*W(NxK)^T tile; KU k-sub-tiles (64 each) per barrier ----
// As size: BM*64*KU bf16;  Bs size: 128*64*KU bf16.  XOR-swizzle q^(r&7) per 16B chunk.
template<int BM, int KU>
__device__ __forceinline__ void gemm_core(
    const bf16* __restrict__ Ab, int lda,
    const bf16* __restrict__ Wb, int ldw,
    int K, int m0, int n0, int tid,
    bf16* As, bf16* Bs,
    f32_4 (&acc)[4][(BM == 128) ? 4 : 2])
{
    constexpr int NJ = (BM == 128) ? 4 : 2;
    constexpr int CA = BM * 8;
    const int lane = tid & 63;
    const int wave = tid >> 6;
    const int l15  = lane & 15;
    const int quad = lane >> 4;
    const int WM = (BM == 128) ? (wave >> 1) * 64 : 0;
    const int WN = (BM == 128) ? (wave & 1) * 64 : wave * 32;

#pragma unroll
    for (int i = 0; i < 4; i++)
#pragma unroll
        for (int j = 0; j < NJ; j++) acc[i][j] = (f32_4)(0.0f);

    for (int k0 = 0; k0 < K; k0 += 64 * KU) {
#pragma unroll
        for (int ku = 0; ku < KU; ++ku) {
            bf16* Asu = As + ku * BM * 64;
            bf16* Bsu = Bs + ku * 128 * 64;
            int kk = k0 + ku * 64;
#pragma unroll
            for (int it = 0; it < CA / 256; ++it) {
                int p = wave * (CA / 4) + it * 64 + lane;
                int r = p >> 3;
                int q = (p & 7) ^ (r & 7);
                GLDS16(Ab + (long long)(m0 + r) * lda + kk + q * 8, Asu + p * 8);
            }
#pragma unroll
            for (int it = 0; it < 4; ++it) {
                int p = wave * 256 + it * 64 + lane;
                int r = p >> 3;
                int q = (p & 7) ^ (r & 7);
                GLDS16(Wb + (long long)(n0 + r) * ldw + kk + q * 8, Bsu + p * 8);
            }
        }
        __syncthreads();

#pragma unroll
        for (int ku = 0; ku < KU; ++ku) {
            bf16* Asu = As + ku * BM * 64;
            bf16* Bsu = Bs + ku * 128 * 64;
#pragma unroll
            for (int kh = 0; kh < 2; ++kh) {
                bf16_8 af[4], bfr[NJ];
#pragma unroll
                for (int t = 0; t < 4; ++t) {
                    int r = WM + t * 16 + l15;
                    int q = (kh * 4 + quad) ^ (r & 7);
                    af[t] = *reinterpret_cast<const bf16_8*>(&Asu[r * 64 + q * 8]);
                }
#pragma unroll
                for (int j = 0; j < NJ; ++j) {
                    int r = WN + j * 16 + l15;
                    int q = (kh * 4 + quad) ^ (r & 7);
                    bfr[j] = *reinterpret_cast<const bf16_8*>(&Bsu[r * 64 + q * 8]);
                }
#pragma unroll
                for (int i = 0; i < 4; ++i)
#pragma unroll
                    for (int j = 0; j < NJ; ++j)
                        acc[i][j] = __builtin_amdgcn_mfma_f32_16x16x32_bf16(af[i], bfr[j], acc[i][j], 0, 0, 0);
            }
        }
        __syncthreads();
    }
}

// -------- merged projections: V full + Q/K head-1 (BK=128) --------
__global__ __launch_bounds__(256) void proj_merged(
    const bf16* __restrict__ x_bf,
    const bf16* __restrict__ wv_bf, const float* __restrict__ bv, bf16* __restrict__ v_bf,
    const bf16* __restrict__ wq_bf, const float* __restrict__ bq, bf16* __restrict__ qh1,
    const bf16* __restrict__ wk_bf, const float* __restrict__ bk, bf16* __restrict__ kh1)
{
    __shared__ alignas(16) bf16 As[64 * 64 * 2];
    __shared__ alignas(16) bf16 Bs[128 * 64 * 2];
    const int tid = threadIdx.x;
    const int lane = tid & 63, wave = tid >> 6, l15 = lane & 15, quad = lane >> 4;
    const int n0 = blockIdx.x * 128;

    int m0;
    const bf16* Ab; const bf16* Wb; const float* bvec; bf16* op;
    long long obase;
    int y = blockIdx.y;
    if (y < 64) { m0 = y * 64; Ab = x_bf; Wb = wv_bf; bvec = bv; op = v_bf; obase = 0; }
    else {
        int sub = y - 64;
        int batch = (sub >> 1) & 1;
        int sel = sub >> 2;
        m0 = (sub & 1) * 64;
        Ab = x_bf + (long long)batch * 2097152LL + 131072LL;   // rows 128..255 of batch slab
        Wb = sel ? wk_bf : wq_bf;
        bvec = sel ? bk : bq;
        op = sel ? kh1 : qh1;
        obase = (long long)batch * 131072LL;
    }

    f32_4 acc[4][2];
    gemm_core<64, 2>(Ab, 1024, Wb, 1024, 1024, m0, n0, tid, As, Bs, acc);

    const int WN = wave * 32;
#pragma unroll
    for (int i = 0; i < 4; i++)
#pragma unroll
        for (int j = 0; j < 2; j++)
#pragma unroll
            for (int rg = 0; rg < 4; rg++) {
                int m = m0 + i * 16 + quad * 4 + rg;
                int n = n0 + WN + j * 16 + l15;
                op[obase + (long long)m * 1024 + n] = (bf16)(acc[i][j][rg] + bvec[n]);
            }
}

// -------- scores head-1 + exp + row partials, THEN inline V transpose (BK=64, K=64) ---
__global__ __launch_bounds__(256) void scores_tr(
    const bf16* __restrict__ qh1, const bf16* __restrict__ kh1,
    const float* __restrict__ slopes,
    bf16* __restrict__ pb, float* __restrict__ spart,
    const unsigned short* __restrict__ v_bf, unsigned short* __restrict__ vt)
{
    __shared__ alignas(16) char smem[32768];
    bf16* As = (bf16*)smem;
    bf16* Bs = (bf16*)(smem + 16384);
    const int tid = threadIdx.x;
    const int lane = tid & 63, wave = tid >> 6, l15 = lane & 15, quad = lane >> 4;
    const int n0 = blockIdx.x * 128;
    const int m0 = blockIdx.y * 128;
    const int z  = blockIdx.z;

    f32_4 acc[4][4];
    gemm_core<128, 1>(qh1 + (long long)z * 131072LL, 64,
                      kh1 + (long long)z * 131072LL, 64, 64, m0, n0, tid, As, Bs, acc);

    const int WM = (wave >> 1) * 64;
    const int WN = (wave & 1) * 64;
    const float slope = slopes[1];
    long long obase = (long long)z * 4194304LL;
#pragma unroll
    for (int i = 0; i < 4; i++) {
#pragma unroll
        for (int rg = 0; rg < 4; rg++) {
            int m = m0 + WM + i * 16 + quad * 4 + rg;
            float rowpart = 0.0f;
#pragma unroll
            for (int j = 0; j < 4; j++) {
                int n = n0 + WN + j * 16 + l15;
                float v = acc[i][j][rg] * 0.125f - slope * fabsf((float)(m - n));
                float e = __expf(v);
                rowpart += e;
                pb[obase + (long long)m * 2048 + n] = (bf16)e;
            }
            rowpart += __shfl_xor(rowpart, 1, 64);
            rowpart += __shfl_xor(rowpart, 2, 64);
            rowpart += __shfl_xor(rowpart, 4, 64);
            rowpart += __shfl_xor(rowpart, 8, 64);
            if (l15 == 0)
                spart[((long long)z * 2048 + m) * 32 + (n0 >> 6) + (WN >> 6)] = rowpart;
        }
    }

    // ---- inline V transpose (flat-reshape mapping), 2 of 1024 tiles per block ----
    unsigned short* tile = (unsigned short*)smem;    // As region free after gemm_core
    int flat = z * 256 + blockIdx.y * 16 + blockIdx.x;   // 0..511
#pragma unroll
    for (int uu = 0; uu < 2; ++uu) {
        int u = flat * 2 + uu;                           // 0..1023
        int k0 = (u & 31) * 64, h = (u >> 5) & 15, b = u >> 9;
        const unsigned short* src = v_bf + (long long)b * 2097152LL + (long long)h * 131072LL;
#pragma unroll
        for (int p = 0; p < 8; p++) {
            int idx = tid + p * 256;
            int k = idx >> 5, dc = idx & 31;
            ushort2 w = *reinterpret_cast<const ushort2*>(&src[(long long)(k0 + k) * 64 + dc * 2]);
            tile[(dc * 2) * 66 + k]     = w.x;
            tile[(dc * 2 + 1) * 66 + k] = w.y;
        }
        __syncthreads();
        unsigned short* dst = vt + (long long)b * 2097152LL + (long long)h * 64 * 2048LL + k0;
#pragma unroll
        for (int p = 0; p < 8; p++) {
            int idx = tid + p * 256;
            int d = idx >> 5, kc = idx & 31;
            ushort2 w;
            w.x = tile[d * 66 + kc * 2];
            w.y = tile[d * 66 + kc * 2 + 1];
            *reinterpret_cast<ushort2*>(&dst[(long long)d * 2048 + kc * 2]) = w;
        }
        __syncthreads();
    }
}

// -------- PV fused (BK=128): rsinv prologue + probs_f writes in-loop + attn scatter ---
__global__ __launch_bounds__(256) void pv_fused(
    const bf16* __restrict__ pb, const bf16* __restrict__ vt,
    const float* __restrict__ spart,
    bf16* __restrict__ attn, float* __restrict__ probs_f)
{
    __shared__ alignas(16) bf16 As[64 * 64 * 2];
    __shared__ alignas(16) bf16 Bs[128 * 64 * 2];
    __shared__ float rs[64];
    const int tid = threadIdx.x;
    const int lane = tid & 63, wave = tid >> 6, l15 = lane & 15, quad = lane >> 4;
    const int nx = blockIdx.x;          // n-tile AND probs k-slice index (both 8-wide)
    const int n0 = nx * 128;
    const int m0 = blockIdx.y * 64;
    const int z  = blockIdx.z;

    // prologue: rs[r] = 1 / sum_j spart[z*2048+m0+r][j]
    {
        int r = tid >> 2, part = tid & 3;
        const float* sp = spart + ((long long)z * 2048 + m0 + r) * 32 + part * 8;
        float4 a = *reinterpret_cast<const float4*>(sp);
        float4 b = *reinterpret_cast<const float4*>(sp + 4);
        float v = a.x + a.y + a.z + a.w + b.x + b.y + b.z + b.w;
        v += __shfl_xor(v, 1, 64);
        v += __shfl_xor(v, 2, 64);
        if (part == 0) rs[r] = 1.0f / v;
    }
    __syncthreads();

    const bf16* Ab = pb + (long long)z * 4194304LL;
    const bf16* Wb = vt + (long long)z * 2097152LL;

    f32_4 acc[4][2];
#pragma unroll
    for (int i = 0; i < 4; i++)
#pragma unroll
        for (int j = 0; j < 2; j++) acc[i][j] = (f32_4)(0.0f);

    for (int k0 = 0; k0 < 2048; k0 += 128) {
#pragma unroll
        for (int ku = 0; ku < 2; ++ku) {
            bf16* Asu = As + ku * 4096;
            bf16* Bsu = Bs + ku * 8192;
            int kk = k0 + ku * 64;
#pragma unroll
            for (int it = 0; it < 2; ++it) {
                int p = wave * 128 + it * 64 + lane;
                int r = p >> 3, q = (p & 7) ^ (r & 7);
                GLDS16(Ab + (long long)(m0 + r) * 2048 + kk + q * 8, Asu + p * 8);
            }
#pragma unroll
            for (int it = 0; it < 4; ++it) {
                int p = wave * 256 + it * 64 + lane;
                int r = p >> 3, q = (p & 7) ^ (r & 7);
                GLDS16(Wb + (long long)(n0 + r) * 2048 + kk + q * 8, Bsu + p * 8);
            }
        }
        __syncthreads();

        // write probs_f (f32, normalized) for sub-tiles in this block's 256-col k-slice
#pragma unroll
        for (int ku = 0; ku < 2; ++ku) {
            int kk = k0 + ku * 64;
            if ((kk >> 8) == nx) {
                bf16* Asu = As + ku * 4096;
#pragma unroll
                for (int s0 = 0; s0 < 2; ++s0) {
                    int s = tid + s0 * 256;          // 0..511
                    int r = s >> 3, q = s & 7;
                    bf16_8 e = *reinterpret_cast<const bf16_8*>(&Asu[r * 64 + (q ^ (r & 7)) * 8]);
                    float inv = rs[r];
                    float4 o0, o1;
                    o0.x = (float)e[0] * inv; o0.y = (float)e[1] * inv;
                    o0.z = (float)e[2] * inv; o0.w = (float)e[3] * inv;
                    o1.x = (float)e[4] * inv; o1.y = (float)e[5] * inv;
                    o1.z = (float)e[6] * inv; o1.w = (float)e[7] * inv;
                    long long base = ((long long)z * 2048 + m0 + r) * 2048 + kk + q * 8;
                    *reinterpret_cast<float4*>(&probs_f[base])     = o0;
                    *reinterpret_cast<float4*>(&probs_f[base + 4]) = o1;
                }
            }
        }

#pragma unroll
        for (int ku = 0; ku < 2; ++ku) {
            bf16* Asu = As + ku * 4096;
            bf16* Bsu = Bs + ku * 8192;
#pragma unroll
            for (int kh = 0; kh < 2; ++kh) {
                bf16_8 af[4], bfr[2];
#pragma unroll
                for (int t = 0; t < 4; ++t) {
                    int r = t * 16 + l15;
                    int q = (kh * 4 + quad) ^ (r & 7);
                    af[t] = *reinterpret_cast<const bf16_8*>(&Asu[r * 64 + q * 8]);
                }
                const int WN = wave * 32;
#pragma unroll
                for (int j = 0; j < 2; ++j) {
                    int r = WN + j * 16 + l15;
                    int q = (kh * 4 + quad) ^ (r & 7);
                    bfr[j] = *reinterpret_cast<const bf16_8*>(&Bsu[r * 64 + q * 8]);
                }
#pragma unroll
                for (int i = 0; i < 4; ++i)
#pragma unroll
                    for (int j = 0; j < 2; ++j)
                        acc[i][j] = __builtin_amdgcn_mfma_f32_16x16x32_bf16(af[i], bfr[j], acc[i][j], 0, 0, 0);
            }
        }
        __syncthreads();
    }

    // epilogue: scale by rs[row], scatter to flat attn layout
    const int WN = wave * 32;
    long long obase = (long long)z * 2097152LL;
#pragma unroll
    for (int i = 0; i < 4; i++)
#pragma unroll
        for (int j = 0; j < 2; j++)
#pragma unroll
            for (int rg = 0; rg < 4; rg++) {
                int ml = i * 16 + quad * 4 + rg;
                int m = m0 + ml;
                int n = n0 + WN + j * 16 + l15;
                float v = acc[i][j][rg] * rs[ml];
                long long off = obase + ((long long)(n >> 6)) * 131072LL + (long long)m * 64 + (n & 63);
                attn[off] = (bf16)v;
            }
}

// -------- out projection (BK=128): f32 out + bias --------
__global__ __launch_bounds__(256) void out_proj(
    const bf16* __restrict__ attn, const bf16* __restrict__ wo_bf,
    const float* __restrict__ bo, float* __restrict__ out_f)
{
    __shared__ alignas(16) bf16 As[64 * 64 * 2];
    __shared__ alignas(16) bf16 Bs[128 * 64 * 2];
    const int tid = threadIdx.x;
    const int lane = tid & 63, wave = tid >> 6, l15 = lane & 15, quad = lane >> 4;
    const int n0 = blockIdx.x * 128;
    const int m0 = blockIdx.y * 64;

    f32_4 acc[4][2];
    gemm_core<64, 2>(attn, 1024, wo_bf, 1024, 1024, m0, n0, tid, As, Bs, acc);

    const int WN = wave * 32;
#pragma unroll
    for (int i = 0; i < 4; i++)
#pragma unroll
        for (int j = 0; j < 2; j++)
#pragma unroll
            for (int rg = 0; rg < 4; rg++) {
                int m = m0 + i * 16 + quad * 4 + rg;
                int n = n0 + WN + j * 16 + l15;
                out_f[(long long)m * 1024 + n] = acc[i][j][rg] + bo[n];
            }
}

// ---------------- launcher: 5 launches ----------------
extern "C" void kernel_launch(void* const* d_in, const int* in_sizes, int n_in,
                              void* d_out, int out_size, void* d_ws, size_t ws_size,
                              hipStream_t stream) {
    const float* x      = (const float*)d_in[0];
    const float* Wq     = (const float*)d_in[1];
    const float* bq     = (const float*)d_in[2];
    const float* Wk     = (const float*)d_in[3];
    const float* bk     = (const float*)d_in[4];
    const float* Wv     = (const float*)d_in[5];
    const float* bv     = (const float*)d_in[6];
    const float* Wo     = (const float*)d_in[7];
    const float* bo     = (const float*)d_in[8];
    const float* slopes = (const float*)d_in[9];

    // B=2, S=2048, E=1024, H=16, hd=64
    char* w = (char*)d_ws;
    bf16* x_bf  = (bf16*)w;  w += 4096LL * 1024 * 2;
    bf16* wq_bf = (bf16*)w;  w += 1024LL * 1024 * 2;
    bf16* wk_bf = (bf16*)w;  w += 1024LL * 1024 * 2;
    bf16* wv_bf = (bf16*)w;  w += 1024LL * 1024 * 2;
    bf16* wo_bf = (bf16*)w;  w += 1024LL * 1024 * 2;
    bf16* qh1   = (bf16*)w;  w += 2LL * 131072 * 2;
    bf16* kh1   = (bf16*)w;  w += 2LL * 131072 * 2;
    bf16* v_bf  = (bf16*)w;  w += 4096LL * 1024 * 2;
    bf16* vt    = (bf16*)w;  w += 2LL * 1024 * 2048 * 2;
    bf16* attn  = (bf16*)w;  w += 4096LL * 1024 * 2;
    bf16* pb    = (bf16*)w;  w += 2LL * 2048 * 2048 * 2;
    float* spart = (float*)w; w += 4096LL * 32 * 4;

    float* out_f   = (float*)d_out;                // (B,S,E)
    float* probs_f = (float*)d_out + 4194304LL;    // (B,1,S,S)

    // 1) converts
    convert_all<<<2048, 256, 0, stream>>>(x, Wq, Wk, Wv, Wo, x_bf, wq_bf, wk_bf, wv_bf, wo_bf);

    // 2) merged projections: V full + Q/K head-1
    proj_merged<<<dim3(8, 72, 1), 256, 0, stream>>>(
        x_bf, wv_bf, bv, v_bf, wq_bf, bq, qh1, wk_bf, bk, kh1);

    // 3) scores + exp + spart, then inline V transpose
    scores_tr<<<dim3(16, 16, 2), 256, 0, stream>>>(
        qh1, kh1, slopes, pb, spart,
        (const unsigned short*)v_bf, (unsigned short*)vt);

    // 4) PV fused: rsinv from spart, probs_f (d_out), attn scatter
    pv_fused<<<dim3(8, 32, 2), 256, 0, stream>>>(pb, vt, spart, attn, probs_f);

    // 5) out projection -> d_out
    out_proj<<<dim3(8, 64, 1), 256, 0, stream>>>(attn, wo_bf, bo, out_f);
}